// Round 8
// baseline (491.620 us; speedup 1.0000x reference)
//
#include <hip/hip_runtime.h>
#include <cstdint>

typedef unsigned short u16;
typedef unsigned int u32;
typedef __attribute__((ext_vector_type(8))) __bf16 bf16x8;
typedef __attribute__((ext_vector_type(4))) float f32x4;
typedef __attribute__((ext_vector_type(4))) unsigned short u16x4;

#define AS1 __attribute__((address_space(1)))
#define AS3 __attribute__((address_space(3)))

__device__ __forceinline__ void gload16(const void* g, void* l) {
    __builtin_amdgcn_global_load_lds((AS1 void*)g, (AS3 void*)l, 16, 0, 0);
}

// hardware bf16 convert (gfx950 v_cvt_pk_bf16_f32), RNE — same semantics as sw version
__device__ __forceinline__ u16 f2bf(float f) {
    return __builtin_bit_cast(u16, (__bf16)f);
}

__device__ __forceinline__ void store_c(u16* p, float v)   { *p = f2bf(v); }
__device__ __forceinline__ void store_c(float* p, float v) { *p = v; }

// ---------------------------------------------------------------------------
// Fused prep: cvt_bf16 + 4x transpose_cvt in one launch (blockIdx.z role).
// ---------------------------------------------------------------------------
__global__ __launch_bounds__(256) void prep(
    const float* __restrict__ x,  const float* __restrict__ Wq,
    const float* __restrict__ Wk, const float* __restrict__ Wv,
    const float* __restrict__ Wo,
    u16* __restrict__ xb, u16* __restrict__ WqkvT, u16* __restrict__ WoT)
{
    __shared__ float tile[32][33];
    const int z = blockIdx.z;
    const int tx = threadIdx.x, ty = threadIdx.y;   // (32, 8)

    if (z >= 4) {   // x -> xb bf16 convert (8192 virtual blocks x 1024 elems)
        int gb  = (z - 4) * 4096 + blockIdx.y * 64 + blockIdx.x;
        int i   = (gb * 256 + ty * 32 + tx) * 4;
        float4 v = *(const float4*)(x + i);
        u16x4 o = { f2bf(v.x), f2bf(v.y), f2bf(v.z), f2bf(v.w) };
        *(u16x4*)(xb + i) = o;
        return;
    }

    const float* in; u16* out; int C;
    if (z == 0)      { in = Wq; out = WqkvT;                         C = 2048; }
    else if (z == 1) { in = Wk; out = WqkvT + (size_t)2048 * 2048;   C = 512;  }
    else if (z == 2) { in = Wv; out = WqkvT + (size_t)2560 * 2048;   C = 512;  }
    else             { in = Wo; out = WoT;                           C = 2048; }

    int c0 = blockIdx.x * 32, r0 = blockIdx.y * 32;
    if (c0 >= C) return;   // Wk/Wv are only 512 cols wide
#pragma unroll
    for (int i = 0; i < 32; i += 8)
        tile[ty + i][tx] = in[(size_t)(r0 + ty + i) * C + c0 + tx];
    __syncthreads();
#pragma unroll
    for (int i = 0; i < 32; i += 8)
        out[(size_t)(c0 + ty + i) * 2048 + r0 + tx] = f2bf(tile[tx][ty + i]);
}

// V columns of QKVb [4096][3072] (cols 2560..3071) -> VT [b][kv*128][2048]
__global__ void vtrans(const u16* __restrict__ QKV, u16* __restrict__ VT) {
    __shared__ u16 tile[32][33];
    int b = blockIdx.z;
    int c0 = blockIdx.x * 32, r0 = blockIdx.y * 32;
    int tx = threadIdx.x, ty = threadIdx.y;
#pragma unroll
    for (int i = 0; i < 32; i += 8)
        tile[ty + i][tx] = QKV[(size_t)(b * 2048 + r0 + ty + i) * 3072 + 2560 + c0 + tx];
    __syncthreads();
#pragma unroll
    for (int i = 0; i < 32; i += 8)
        VT[(size_t)(b * 512 + c0 + ty + i) * 2048 + r0 + tx] = tile[tx][ty + i];
}

// ---------------------------------------------------------------------------
// C[M][N] = A[M][K] @ Bt[N][K]^T, bf16 in, fp32 accum. XOR-swizzled LDS.
// ---------------------------------------------------------------------------
template <typename OT>
__global__ __launch_bounds__(256, 2) void gemm_bt(
    const u16* __restrict__ A, const u16* __restrict__ Bt,
    OT* __restrict__ C, int M, int N, int K)
{
    __shared__ u16 As[128 * 64];
    __shared__ u16 Bs[128 * 64];
    const int tid  = threadIdx.x;
    const int wave = tid >> 6, lane = tid & 63;
    const int quad = lane >> 4, l15 = lane & 15;
    const int bm0 = blockIdx.y * 128, bn0 = blockIdx.x * 128;
    const int wr = (wave >> 1) * 64, wc = (wave & 1) * 64;

    const f32x4 zero = {0.f, 0.f, 0.f, 0.f};
    f32x4 acc[4][4];
#pragma unroll
    for (int i = 0; i < 4; ++i)
#pragma unroll
        for (int j = 0; j < 4; ++j) acc[i][j] = zero;

    const int srow = lane >> 3;
    const int jsw  = ((lane & 7) ^ srow) * 8;

    for (int k0 = 0; k0 < K; k0 += 64) {
#pragma unroll
        for (int i = 0; i < 4; ++i) {
            int c = wave * 4 + i;
            gload16(A  + (size_t)(bm0 + c * 8 + srow) * K + k0 + jsw, As + c * 512);
            gload16(Bt + (size_t)(bn0 + c * 8 + srow) * K + k0 + jsw, Bs + c * 512);
        }
        __syncthreads();
#pragma unroll
        for (int ks = 0; ks < 2; ++ks) {
            bf16x8 a[4], b[4];
#pragma unroll
            for (int t = 0; t < 4; ++t) {
                int rd = ((ks * 4 + quad) ^ (l15 & 7)) * 8;
                a[t] = *(const bf16x8*)(As + (wr + t * 16 + l15) * 64 + rd);
                b[t] = *(const bf16x8*)(Bs + (wc + t * 16 + l15) * 64 + rd);
            }
#pragma unroll
            for (int i = 0; i < 4; ++i)
#pragma unroll
                for (int j = 0; j < 4; ++j)
                    acc[i][j] = __builtin_amdgcn_mfma_f32_16x16x32_bf16(a[i], b[j], acc[i][j], 0, 0, 0);
        }
        __syncthreads();
    }
#pragma unroll
    for (int i = 0; i < 4; ++i) {
        int grow = bm0 + wr + i * 16 + quad * 4;
#pragma unroll
        for (int j = 0; j < 4; ++j) {
            int gcol = bn0 + wc + j * 16 + l15;
#pragma unroll
            for (int r = 0; r < 4; ++r)
                store_c(&C[(size_t)(grow + r) * N + gcol], acc[i][j][r]);
        }
    }
}

// ---------------------------------------------------------------------------
// Flash attention, causal, GQA. R8 restructure for TLP (the R7 post-mortem
// refuted the LDS-issue theory: -41% ds_reads made it SLOWER; the wall is
// barrier-chained stall at ~2 blocks/CU + solo-block tails).
//
//  - 256 threads / 4 waves, ONE q-tile (64 rows) per block; grid (32,32) =
//    1024 blocks. All waves active every iteration; dynamic backfill over
//    1024 short jobs replaces static pairing (no solo tails).
//  - Vs LDS staging DROPPED: PV reads V directly from VT. The R6 stage+read
//    XOR swizzles cancel exactly (net global col = (ks2*4+quad)*8), so the
//    fragment values are identical. VT slice per (b,kv) = 512KB, L2-resident.
//  - LDS = Ks 32K + Ps 9K = 41KB -> 3 blocks/CU (12 waves, 3/SIMD, VGPR cap
//    170 >> ~100 needed). launch_bounds(256,3).
//  - ONE __syncthreads per iteration (was 2 barriers): only cross-wave dep is
//    the Ks tile; its vmcnt(0) drain lands the K-prefetch issued at the top
//    of the same iteration (whole QK^T+softmax+PV to fly).
// K staging, QK^T reads, softmax, P layout, PV math, epilogue: R6 verbatim
// (per-wave role w4 -> wave). Summation order unchanged -> identical output.
// ---------------------------------------------------------------------------
__global__ __launch_bounds__(256, 3) void attn(
    const u16* __restrict__ QKV, const u16* __restrict__ VT, u16* __restrict__ Y)
{
    __shared__ u16 Ks[2][64 * 128];   // [key][d], chunk-swizzled   32KB
    __shared__ u16 Ps[4][16 * 72];    // per-wave P, LD=72           9KB

    const int tid  = threadIdx.x;
    const int wave = tid >> 6, lane = tid & 63;   // wave 0..3
    const int quad = lane >> 4, l15 = lane & 15;
    const int qt = blockIdx.x;                 // q-tile 0..31
    const int bh = blockIdx.y;
    const int b = bh >> 4, h = bh & 15, kv = h >> 2;
    const int q0 = qt * 64 + wave * 16;

    bf16x8 aq[4];
    {
        const u16* qp = QKV + (size_t)(b * 2048 + q0 + l15) * 3072 + h * 128 + quad * 8;
#pragma unroll
        for (int ks = 0; ks < 4; ++ks) aq[ks] = *(const bf16x8*)(qp + ks * 32);
    }

    bf16x8 ones;
#pragma unroll
    for (int i = 0; i < 8; ++i) ones[i] = __builtin_bit_cast(__bf16, (u16)0x3F80);

    const f32x4 zero = {0.f, 0.f, 0.f, 0.f};
    f32x4 o[9];
#pragma unroll
    for (int i = 0; i < 9; ++i) o[i] = zero;

    const u16* Kbase = QKV + 2048 + kv * 128;                      // + row*3072
    const u16* Vbase = VT + (size_t)((b * 4 + kv) * 128) * 2048;   // + d*2048
    u16* pw = &Ps[wave][0];

    const int kr = lane >> 4;

    // 16 K-chunks (4 rows x 128 cols each), 4 per wave
    auto stageK = [&](int buf, int kt) {
#pragma unroll
        for (int i = 0; i < 4; ++i) {
            int ci = wave * 4 + i;
            int krow = ci * 4 + kr;
            int kjs = ((lane & 15) ^ (krow & 15)) * 8;
            gload16(Kbase + (size_t)(b * 2048 + kt * 64 + krow) * 3072 + kjs,
                    &Ks[buf][ci * 512]);
        }
    };

    const float c1 = 0.12752817f;    // (1/sqrt(128)) * log2(e)
    const float c2 = 28.85390082f;   // 20 * log2(e)

    stageK(0, 0);
    __syncthreads();

    for (int kt = 0; kt <= qt; ++kt) {
        const int cur = kt & 1;
        if (kt < qt) stageK(cur ^ 1, kt + 1);    // dbuf prefetch into other buf

        const u16* Ksc = &Ks[cur][0];

        // QK^T: S[16 own rows][all 64 keys]
        {
            f32x4 s[4];
#pragma unroll
            for (int i = 0; i < 4; ++i) s[i] = zero;
            __builtin_amdgcn_s_setprio(1);
#pragma unroll
            for (int ks = 0; ks < 4; ++ks)
#pragma unroll
                for (int kc = 0; kc < 4; ++kc) {
                    bf16x8 bk = *(const bf16x8*)(Ksc + (kc * 16 + l15) * 128 + (((ks * 4 + quad) ^ l15) * 8));
                    s[kc] = __builtin_amdgcn_mfma_f32_16x16x32_bf16(aq[ks], bk, s[kc], 0, 0, 0);
                }
            __builtin_amdgcn_s_setprio(0);
            const bool diag = (kt == qt);
#pragma unroll
            for (int kc = 0; kc < 4; ++kc)
#pragma unroll
                for (int r = 0; r < 4; ++r) {
                    float arg = fmaf(s[kc][r], c1, -c2);
                    if (diag && (kc * 16 + l15) > (wave * 16 + quad * 4 + r)) arg = -10000.f;
                    float p = __builtin_amdgcn_exp2f(arg);
                    pw[(quad * 4 + r) * 72 + kc * 16 + l15] = f2bf(p);
                }
            asm volatile("" ::: "memory");
        }

        // PV: bv straight from global VT (stage/read swizzles cancel:
        // value = VT[(d*16+l15)*2048 + kt*64 + (ks2*4+quad)*8], 16B aligned)
        {
            __builtin_amdgcn_s_setprio(1);
#pragma unroll
            for (int ks2 = 0; ks2 < 2; ++ks2) {
                bf16x8 pa = *(const bf16x8*)(pw + l15 * 72 + ks2 * 32 + quad * 8);
                const u16* vp = Vbase + (size_t)l15 * 2048 + kt * 64 + (ks2 * 4 + quad) * 8;
#pragma unroll
                for (int d = 0; d < 8; ++d) {
                    bf16x8 bv = *(const bf16x8*)(vp + (size_t)d * 16 * 2048);
                    o[d] = __builtin_amdgcn_mfma_f32_16x16x32_bf16(pa, bv, o[d], 0, 0, 0);
                }
                o[8] = __builtin_amdgcn_mfma_f32_16x16x32_bf16(pa, ones, o[8], 0, 0, 0);
            }
            __builtin_amdgcn_s_setprio(0);
        }

        // single barrier: drains K-prefetch (vmcnt0, issued a full phase ago)
        // and retires Ks ds_reads (lgkm0) before next iter's overwrite.
        __syncthreads();
    }

    float inv[4];
#pragma unroll
    for (int r = 0; r < 4; ++r) inv[r] = 1.0f / o[8][r];
#pragma unroll
    for (int d = 0; d < 8; ++d)
#pragma unroll
        for (int r = 0; r < 4; ++r)
            Y[(size_t)(b * 2048 + q0 + quad * 4 + r) * 2048 + h * 128 + d * 16 + l15] =
                f2bf(o[d][r] * inv[r]);
}

// ---------------------------------------------------------------------------
extern "C" void kernel_launch(void* const* d_in, const int* in_sizes, int n_in,
                              void* d_out, int out_size, void* d_ws, size_t ws_size,
                              hipStream_t stream)
{
    const float* x  = (const float*)d_in[0];
    const float* Wq = (const float*)d_in[1];
    const float* Wk = (const float*)d_in[2];
    const float* Wv = (const float*)d_in[3];
    const float* Wo = (const float*)d_in[4];
    float* out = (float*)d_out;

    char* ws = (char*)d_ws;
    u16* xb    = (u16*)ws; ws += (size_t)4096 * 2048 * 2;  // 16MB; reused as Y
    u16* WqkvT = (u16*)ws; ws += (size_t)3072 * 2048 * 2;  // 12MB
    u16* WoT   = (u16*)ws; ws += (size_t)2048 * 2048 * 2;  //  8MB
    u16* QKVb  = (u16*)ws; ws += (size_t)4096 * 3072 * 2;  // 24MB
    u16* VT    = (u16*)ws;                                 //  4MB; total 64MB
    u16* Y     = xb;   // xb dead after QKV GEMM

    dim3 tblk(32, 8, 1);
    // fused: x-cvt + all 4 weight transposes in one launch
    prep<<<dim3(64, 64, 6), tblk, 0, stream>>>(x, Wq, Wk, Wv, Wo, xb, WqkvT, WoT);

    gemm_bt<u16><<<dim3(24, 32, 1), 256, 0, stream>>>(xb, WqkvT, QKVb, 4096, 3072, 2048);

    vtrans<<<dim3(16, 64, 2), tblk, 0, stream>>>(QKVb, VT);

    attn<<<dim3(32, 32, 1), 256, 0, stream>>>(QKVb, VT, Y);

    gemm_bt<float><<<dim3(16, 32, 1), 256, 0, stream>>>(Y, WoT, out, 4096, 2048, 2048);
}

// Round 9
// 268.665 us; speedup vs baseline: 1.8299x; 1.8299x over previous
//
#include <hip/hip_runtime.h>
#include <cstdint>

typedef unsigned short u16;
typedef unsigned int u32;
typedef __attribute__((ext_vector_type(8))) __bf16 bf16x8;
typedef __attribute__((ext_vector_type(4))) float f32x4;
typedef __attribute__((ext_vector_type(4))) unsigned short u16x4;

#define AS1 __attribute__((address_space(1)))
#define AS3 __attribute__((address_space(3)))

__device__ __forceinline__ void gload16(const void* g, void* l) {
    __builtin_amdgcn_global_load_lds((AS1 void*)g, (AS3 void*)l, 16, 0, 0);
}

// hardware bf16 convert (gfx950 v_cvt_pk_bf16_f32), RNE — same semantics as sw version
__device__ __forceinline__ u16 f2bf(float f) {
    return __builtin_bit_cast(u16, (__bf16)f);
}

__device__ __forceinline__ void store_c(u16* p, float v)   { *p = f2bf(v); }
__device__ __forceinline__ void store_c(float* p, float v) { *p = v; }

// ---------------------------------------------------------------------------
// Fused prep: cvt_bf16 + 4x transpose_cvt in one launch (blockIdx.z role).
// ---------------------------------------------------------------------------
__global__ __launch_bounds__(256) void prep(
    const float* __restrict__ x,  const float* __restrict__ Wq,
    const float* __restrict__ Wk, const float* __restrict__ Wv,
    const float* __restrict__ Wo,
    u16* __restrict__ xb, u16* __restrict__ WqkvT, u16* __restrict__ WoT)
{
    __shared__ float tile[32][33];
    const int z = blockIdx.z;
    const int tx = threadIdx.x, ty = threadIdx.y;   // (32, 8)

    if (z >= 4) {   // x -> xb bf16 convert (8192 virtual blocks x 1024 elems)
        int gb  = (z - 4) * 4096 + blockIdx.y * 64 + blockIdx.x;
        int i   = (gb * 256 + ty * 32 + tx) * 4;
        float4 v = *(const float4*)(x + i);
        u16x4 o = { f2bf(v.x), f2bf(v.y), f2bf(v.z), f2bf(v.w) };
        *(u16x4*)(xb + i) = o;
        return;
    }

    const float* in; u16* out; int C;
    if (z == 0)      { in = Wq; out = WqkvT;                         C = 2048; }
    else if (z == 1) { in = Wk; out = WqkvT + (size_t)2048 * 2048;   C = 512;  }
    else if (z == 2) { in = Wv; out = WqkvT + (size_t)2560 * 2048;   C = 512;  }
    else             { in = Wo; out = WoT;                           C = 2048; }

    int c0 = blockIdx.x * 32, r0 = blockIdx.y * 32;
    if (c0 >= C) return;   // Wk/Wv are only 512 cols wide
#pragma unroll
    for (int i = 0; i < 32; i += 8)
        tile[ty + i][tx] = in[(size_t)(r0 + ty + i) * C + c0 + tx];
    __syncthreads();
#pragma unroll
    for (int i = 0; i < 32; i += 8)
        out[(size_t)(c0 + ty + i) * 2048 + r0 + tx] = f2bf(tile[tx][ty + i]);
}

// V columns of QKVb [4096][3072] (cols 2560..3071) -> VT [b][kv*128][2048]
__global__ void vtrans(const u16* __restrict__ QKV, u16* __restrict__ VT) {
    __shared__ u16 tile[32][33];
    int b = blockIdx.z;
    int c0 = blockIdx.x * 32, r0 = blockIdx.y * 32;
    int tx = threadIdx.x, ty = threadIdx.y;
#pragma unroll
    for (int i = 0; i < 32; i += 8)
        tile[ty + i][tx] = QKV[(size_t)(b * 2048 + r0 + ty + i) * 3072 + 2560 + c0 + tx];
    __syncthreads();
#pragma unroll
    for (int i = 0; i < 32; i += 8)
        VT[(size_t)(b * 512 + c0 + ty + i) * 2048 + r0 + tx] = tile[tx][ty + i];
}

// ---------------------------------------------------------------------------
// C[M][N] = A[M][K] @ Bt[N][K]^T, bf16 in, fp32 accum. XOR-swizzled LDS.
// ---------------------------------------------------------------------------
template <typename OT>
__global__ __launch_bounds__(256, 2) void gemm_bt(
    const u16* __restrict__ A, const u16* __restrict__ Bt,
    OT* __restrict__ C, int M, int N, int K)
{
    __shared__ u16 As[128 * 64];
    __shared__ u16 Bs[128 * 64];
    const int tid  = threadIdx.x;
    const int wave = tid >> 6, lane = tid & 63;
    const int quad = lane >> 4, l15 = lane & 15;
    const int bm0 = blockIdx.y * 128, bn0 = blockIdx.x * 128;
    const int wr = (wave >> 1) * 64, wc = (wave & 1) * 64;

    const f32x4 zero = {0.f, 0.f, 0.f, 0.f};
    f32x4 acc[4][4];
#pragma unroll
    for (int i = 0; i < 4; ++i)
#pragma unroll
        for (int j = 0; j < 4; ++j) acc[i][j] = zero;

    const int srow = lane >> 3;
    const int jsw  = ((lane & 7) ^ srow) * 8;

    for (int k0 = 0; k0 < K; k0 += 64) {
#pragma unroll
        for (int i = 0; i < 4; ++i) {
            int c = wave * 4 + i;
            gload16(A  + (size_t)(bm0 + c * 8 + srow) * K + k0 + jsw, As + c * 512);
            gload16(Bt + (size_t)(bn0 + c * 8 + srow) * K + k0 + jsw, Bs + c * 512);
        }
        __syncthreads();
#pragma unroll
        for (int ks = 0; ks < 2; ++ks) {
            bf16x8 a[4], b[4];
#pragma unroll
            for (int t = 0; t < 4; ++t) {
                int rd = ((ks * 4 + quad) ^ (l15 & 7)) * 8;
                a[t] = *(const bf16x8*)(As + (wr + t * 16 + l15) * 64 + rd);
                b[t] = *(const bf16x8*)(Bs + (wc + t * 16 + l15) * 64 + rd);
            }
#pragma unroll
            for (int i = 0; i < 4; ++i)
#pragma unroll
                for (int j = 0; j < 4; ++j)
                    acc[i][j] = __builtin_amdgcn_mfma_f32_16x16x32_bf16(a[i], b[j], acc[i][j], 0, 0, 0);
        }
        __syncthreads();
    }
#pragma unroll
    for (int i = 0; i < 4; ++i) {
        int grow = bm0 + wr + i * 16 + quad * 4;
#pragma unroll
        for (int j = 0; j < 4; ++j) {
            int gcol = bn0 + wc + j * 16 + l15;
#pragma unroll
            for (int r = 0; r < 4; ++r)
                store_c(&C[(size_t)(grow + r) * N + gcol], acc[i][j][r]);
        }
    }
}

// ---------------------------------------------------------------------------
// Flash attention, causal, GQA. 512-thread blocks, 2 q-tiles (2pi, 2pi+1),
// waves 0-3 -> tile A, waves 4-7 -> tile B. Fixed-max softmax
// (p = exp2(s*c1 - c2)), MFMA-accumulated denominator.
//
// R9: single-barrier iteration. Rate law from R1/R6/R8: per-block iteration
// ~1.8-2.0us regardless of co-residency => the cost is the block's SERIAL
// chain (2 barrier drains + straggle), not CU throughput (R7: fewer LDS reads
// didn't help; R8: global-V lengthened the chain, 5x slower). Fix: Vs double-
// buffered like Ks, both prefetched one tile ahead => the softmax->PV handoff
// is wave-private (Ps is per-wave) and needs NO barrier; ONE __syncthreads
// per iteration (its vmcnt(0) drain lands stages issued a full iteration ago;
// its lgkm drain + barrier protect buffer (kt+1)&1, last read in iter kt-1).
//
// LDS budget for 2 blocks/CU is exactly 80KB: Ks dbuf 32K + Vs dbuf 32K +
// Ps 16K = 81920B. Ps loses its pad-72 (18K->16K) via an XOR granule swizzle
// on unpadded [16][64]: granule (col>>3) ^ (row&7), same XOR on read.
// pa b128 reads: 2 lanes/bank (free); P b16 writes ~4-way (stores, cheap).
// Single exact-sized SMEM array prevents compiler padding past 81920.
// Summation order unchanged -> bit-identical Y (absmax must stay 0.015625).
// ---------------------------------------------------------------------------
__global__ __launch_bounds__(512, 4) void attn(
    const u16* __restrict__ QKV, const u16* __restrict__ VT, u16* __restrict__ Y)
{
    // [0,16384): Ks dbuf 2x[64][128]  (chunk-swizzled)
    // [16384,32768): Vs dbuf 2x[128][64] (chunk-swizzled)
    // [32768,40960): Ps 8 waves x [16][64] (granule XOR swizzle)
    __shared__ u16 SMEM[40960];   // 81920 B exactly = 160KB/2

    const int tid  = threadIdx.x;
    const int wave = tid >> 6, lane = tid & 63;   // wave 0..7
    const int quad = lane >> 4, l15 = lane & 15;
    const int w4 = wave & 3;
    int pi = blockIdx.x;                       // 0..15
    const int bh = blockIdx.y;
    if (bh >= 16) pi = 15 - pi;                // anti-correlate CU's two blocks
    const int qtA = 2 * pi, qtB = 2 * pi + 1;
    const int b = bh >> 4, h = bh & 15, kv = h >> 2;

    const int myqt = (wave < 4) ? qtA : qtB;
    const int q0 = myqt * 64 + w4 * 16;

    bf16x8 aq[4];
    {
        const u16* qp = QKV + (size_t)(b * 2048 + q0 + l15) * 3072 + h * 128 + quad * 8;
#pragma unroll
        for (int ks = 0; ks < 4; ++ks) aq[ks] = *(const bf16x8*)(qp + ks * 32);
    }

    bf16x8 ones;
#pragma unroll
    for (int i = 0; i < 8; ++i) ones[i] = __builtin_bit_cast(__bf16, (u16)0x3F80);

    const f32x4 zero = {0.f, 0.f, 0.f, 0.f};
    f32x4 o[9];
#pragma unroll
    for (int i = 0; i < 9; ++i) o[i] = zero;

    const u16* Kbase = QKV + 2048 + kv * 128;                      // + row*3072
    const u16* Vbase = VT + (size_t)((b * 4 + kv) * 128) * 2048;   // + d*2048
    u16* pw = SMEM + 32768 + wave * 1024;   // this wave's P: [16][64] swizzled

    const int kr = lane >> 4;
    const int vr = lane >> 3;
    const int vjs = ((lane & 7) ^ vr) * 8;

    // 16 chunks each for Ks/Vs tiles, 2 per wave
    auto stageK = [&](int buf, int kt) {
        u16* dst = SMEM + buf * 8192;
#pragma unroll
        for (int i = 0; i < 2; ++i) {
            int ci = wave * 2 + i;
            int krow = ci * 4 + kr;
            int kjs = ((lane & 15) ^ (krow & 15)) * 8;
            gload16(Kbase + (size_t)(b * 2048 + kt * 64 + krow) * 3072 + kjs,
                    dst + ci * 512);
        }
    };
    auto stageV = [&](int buf, int kt) {
        u16* dst = SMEM + 16384 + buf * 8192;
#pragma unroll
        for (int i = 0; i < 2; ++i) {
            int ci = wave * 2 + i;
            int vrow = ci * 8 + vr;
            gload16(Vbase + (size_t)vrow * 2048 + kt * 64 + vjs, dst + ci * 512);
        }
    };

    const float c1 = 0.12752817f;    // (1/sqrt(128)) * log2(e)
    const float c2 = 28.85390082f;   // 20 * log2(e)

    stageK(0, 0);
    stageV(0, 0);
    __syncthreads();

    for (int kt = 0; kt <= qtB; ++kt) {
        const int cur = kt & 1;
        if (kt < qtB) {                          // prefetch next tile into other
            stageV(cur ^ 1, kt + 1);             // buffers; last read of buf
            stageK(cur ^ 1, kt + 1);             // cur^1 was iter kt-1, guarded
        }                                        // by that iter's barrier.

        const bool act = (kt <= myqt);
        const u16* Ksc = SMEM + cur * 8192;
        const u16* Vsc = SMEM + 16384 + cur * 8192;

        if (act) {
            f32x4 s[4];
#pragma unroll
            for (int i = 0; i < 4; ++i) s[i] = zero;
            __builtin_amdgcn_s_setprio(1);
#pragma unroll
            for (int ks = 0; ks < 4; ++ks)
#pragma unroll
                for (int kc = 0; kc < 4; ++kc) {
                    bf16x8 bk = *(const bf16x8*)(Ksc + (kc * 16 + l15) * 128 + (((ks * 4 + quad) ^ l15) * 8));
                    s[kc] = __builtin_amdgcn_mfma_f32_16x16x32_bf16(aq[ks], bk, s[kc], 0, 0, 0);
                }
            __builtin_amdgcn_s_setprio(0);
            const bool diag = (kt == myqt);
#pragma unroll
            for (int kc = 0; kc < 4; ++kc)
#pragma unroll
                for (int r = 0; r < 4; ++r) {
                    float arg = fmaf(s[kc][r], c1, -c2);
                    if (diag && (kc * 16 + l15) > (w4 * 16 + quad * 4 + r)) arg = -10000.f;
                    float p = __builtin_amdgcn_exp2f(arg);
                    // P store, granule-swizzled: row=quad*4+r, col=kc*16+l15
                    int row = quad * 4 + r;
                    int gsw = ((kc * 2 + (l15 >> 3)) ^ (row & 7)) * 8;
                    pw[row * 64 + gsw + (l15 & 7)] = f2bf(p);
                }
            asm volatile("" ::: "memory");

            // PV: P readback is same-wave (compiler inserts lgkmcnt); Vs(kt)
            // was prefetched last iteration — no barrier needed here.
            __builtin_amdgcn_s_setprio(1);
#pragma unroll
            for (int ks2 = 0; ks2 < 2; ++ks2) {
                bf16x8 pa = *(const bf16x8*)(pw + l15 * 64 + (((ks2 * 4 + quad) ^ (l15 & 7)) * 8));
#pragma unroll
                for (int d = 0; d < 8; ++d) {
                    bf16x8 bv = *(const bf16x8*)(Vsc + (d * 16 + l15) * 64 + (((ks2 * 4 + quad) ^ (l15 & 7)) * 8));
                    o[d] = __builtin_amdgcn_mfma_f32_16x16x32_bf16(pa, bv, o[d], 0, 0, 0);
                }
                o[8] = __builtin_amdgcn_mfma_f32_16x16x32_bf16(pa, ones, o[8], 0, 0, 0);
            }
            __builtin_amdgcn_s_setprio(0);
        }

        // ONE barrier per iteration: drains next-tile stages (vmcnt0, issued
        // a full QK^T+softmax+PV ago) and retires this iter's ds_reads before
        // iter kt+1 overwrites buffer cur^1.
        __syncthreads();
    }

    float inv[4];
#pragma unroll
    for (int r = 0; r < 4; ++r) inv[r] = 1.0f / o[8][r];
#pragma unroll
    for (int d = 0; d < 8; ++d)
#pragma unroll
        for (int r = 0; r < 4; ++r)
            Y[(size_t)(b * 2048 + q0 + quad * 4 + r) * 2048 + h * 128 + d * 16 + l15] =
                f2bf(o[d][r] * inv[r]);
}

// ---------------------------------------------------------------------------
extern "C" void kernel_launch(void* const* d_in, const int* in_sizes, int n_in,
                              void* d_out, int out_size, void* d_ws, size_t ws_size,
                              hipStream_t stream)
{
    const float* x  = (const float*)d_in[0];
    const float* Wq = (const float*)d_in[1];
    const float* Wk = (const float*)d_in[2];
    const float* Wv = (const float*)d_in[3];
    const float* Wo = (const float*)d_in[4];
    float* out = (float*)d_out;

    char* ws = (char*)d_ws;
    u16* xb    = (u16*)ws; ws += (size_t)4096 * 2048 * 2;  // 16MB; reused as Y
    u16* WqkvT = (u16*)ws; ws += (size_t)3072 * 2048 * 2;  // 12MB
    u16* WoT   = (u16*)ws; ws += (size_t)2048 * 2048 * 2;  //  8MB
    u16* QKVb  = (u16*)ws; ws += (size_t)4096 * 3072 * 2;  // 24MB
    u16* VT    = (u16*)ws;                                 //  4MB; total 64MB
    u16* Y     = xb;   // xb dead after QKV GEMM

    dim3 tblk(32, 8, 1);
    // fused: x-cvt + all 4 weight transposes in one launch
    prep<<<dim3(64, 64, 6), tblk, 0, stream>>>(x, Wq, Wk, Wv, Wo, xb, WqkvT, WoT);

    gemm_bt<u16><<<dim3(24, 32, 1), 256, 0, stream>>>(xb, WqkvT, QKVb, 4096, 3072, 2048);

    vtrans<<<dim3(16, 64, 2), tblk, 0, stream>>>(QKVb, VT);

    attn<<<dim3(16, 32, 1), 512, 0, stream>>>(QKVb, VT, Y);

    gemm_bt<float><<<dim3(16, 32, 1), 256, 0, stream>>>(Y, WoT, out, 4096, 2048, 2048);
}